// Round 9
// baseline (134.537 us; speedup 1.0000x reference)
//
#include <hip/hip_runtime.h>

// Problem constants
#define BSZ 16
#define NN  128
#define HH  256
#define LLG 9
#define FFE 48   // edge feature dim (padded to 64 for MFMA K)

typedef float        f32x4 __attribute__((ext_vector_type(4)));
typedef _Float16     f16x8 __attribute__((ext_vector_type(8)));
typedef unsigned int u32x4 __attribute__((ext_vector_type(4)));

static __device__ __forceinline__ unsigned short f2h_bits(float x) {
    _Float16 h = (_Float16)x;   // RNE
    return __builtin_bit_cast(unsigned short, h);
}

static __device__ __forceinline__ float fast_silu(float x) {
    float e = __builtin_amdgcn_exp2f(x * -1.44269504088896341f);
    return x * __builtin_amdgcn_rcpf(1.0f + e);
}

// ---------------------------------------------------------------------------
// Kernel 1: weight transpose + f32->f16 convert.  (proven)
// ---------------------------------------------------------------------------
__global__ __launch_bounds__(256) void pre_w(
    const float* __restrict__ W1, const float* __restrict__ W2,
    unsigned short* __restrict__ W2T, unsigned short* __restrict__ WeT)
{
    int tid = blockIdx.x * 256 + threadIdx.x;   // grid 256 -> 65536 threads
    {
        int ho = tid >> 8, k = tid & 255;
        W2T[(ho << 8) + k] = f2h_bits(W2[(k << 8) + ho]);  // coalesced write
    }
    if (tid < 256 * 64) {
        int h = tid >> 6, f = tid & 63;
        WeT[(h << 6) + f] = (f < FFE) ? f2h_bits(W1[(521 + f) * HH + h])
                                      : (unsigned short)0;
    }
}

// ---------------------------------------------------------------------------
// Kernel 2: pj[b,r,h] = node@Wj ; base[b,r,h] = node@Wi + graph@Wg + b1 (proven)
// ---------------------------------------------------------------------------
__global__ __launch_bounds__(256) void pre_pjbase(
    const float* __restrict__ node, const float* __restrict__ graph,
    const float* __restrict__ W1, const float* __restrict__ b1,
    float* __restrict__ pj, float* __restrict__ base)
{
    __shared__ float nrow[4][HH];
    __shared__ float gsh[LLG];
    const int blk = blockIdx.x;
    const int b = blk >> 5;             // 32 row-groups of 4 per batch
    const int r0 = (blk & 31) << 2;
    const int h = threadIdx.x;

    for (int t = h; t < 4 * HH; t += 256) {
        int r = t >> 8, k = t & 255;
        nrow[r][k] = node[(((size_t)b * NN) + r0 + r) * HH + k];
    }
    if (h < LLG) gsh[h] = graph[b * LLG + h];
    __syncthreads();

    float accj[4] = {0,0,0,0};
    float acci[4] = {0,0,0,0};
    for (int k = 0; k < HH; ++k) {
        float wj = W1[k * HH + h];
        float wi = W1[(k + HH) * HH + h];
        #pragma unroll
        for (int r = 0; r < 4; ++r) {
            float nv = nrow[r][k];
            accj[r] = fmaf(nv, wj, accj[r]);
            acci[r] = fmaf(nv, wi, acci[r]);
        }
    }
    float accg = b1[h];
    #pragma unroll
    for (int l = 0; l < LLG; ++l)
        accg = fmaf(gsh[l], W1[(2 * HH + l) * HH + h], accg);

    #pragma unroll
    for (int r = 0; r < 4; ++r) {
        size_t off = (((size_t)b * NN) + r0 + r) * HH + h;
        pj[off]   = accj[r];
        base[off] = acci[r] + accg;
    }
}

// ---------------------------------------------------------------------------
// Kernel 3: fused main — round-5 base + split-epilogue pipeline:
//   stage(all j); bar; GEMM1(all j); epi1(j 0-63)->h1sA; bar;
//   [ GEMM2(j 0-63)  INTERLEAVED WITH  epi1(j 64-127)->h1sB ]; bar;
//   [ GEMM2(j 64-127) INTERLEAVED WITH epi2-silu(first half) ];
//   epi2(second half); butterfly; store.
// Rationale: VALU time is structural (~42 us) and phases were serialized
// chip-wide (VALUBusy+MfmaUtil+LDS ~= 100%). The interleave lets each wave's
// silu/cvt/ds_write chain co-issue with independent MFMA/ds_read chains.
// ---------------------------------------------------------------------------
__global__ __launch_bounds__(512, 4) void fused_msg(
    const float* __restrict__ edge, const float* __restrict__ pj,
    const float* __restrict__ base, const unsigned short* __restrict__ W2T,
    const unsigned short* __restrict__ WeT, const float* __restrict__ b2,
    float* __restrict__ out)
{
    __shared__ __align__(128) unsigned char lds[81920];
    unsigned char* h1sA = lds;            // 32 KB: h1[j 0-63][h], swizzled
    unsigned char* h1sB = lds + 32768;    // 32 KB: h1[j 64-127][h], swizzled
    unsigned char* efs  = lds + 65536;    // 16 KB: edge[j][f] f16, padded+swizzled

    const int tid  = threadIdx.x;
    const int w    = tid >> 6;         // wave 0..7
    const int lane = tid & 63;
    const int q    = lane >> 4;        // quad 0..3
    const int c    = lane & 15;
    const int bi   = blockIdx.x;       // b*128 + i
    const int b    = bi >> 7;

    const float* eb = edge + (size_t)bi * (NN * FFE);
    const unsigned ck = (unsigned)(c & 7) << 4;      // lane-constant XOR key

    // ---- stage edge block -> f16 LDS (round-5 proven form) ----
    #pragma unroll
    for (int p = 0; p < 3; ++p) {
        const int e4 = p * 512 + tid;            // float4 index, < 1536
        const int j  = e4 / 12;                  // 12 float4 per 48-float row
        const int f4 = e4 - j * 12;              // 0..11
        const f32x4 x = *reinterpret_cast<const f32x4*>(eb + (e4 << 2));
        unsigned int lo = __builtin_bit_cast(unsigned int,
                            __builtin_amdgcn_cvt_pkrtz(x[0], x[1]));
        unsigned int hi = __builtin_bit_cast(unsigned int,
                            __builtin_amdgcn_cvt_pkrtz(x[2], x[3]));
        const unsigned int off = (unsigned)(j << 7) +
            (((unsigned)(f4 << 3)) ^ ((unsigned)(j & 7) << 4));
        *reinterpret_cast<uint2*>(&efs[off]) = make_uint2(lo, hi);
    }
    {   // zero-fill padded f in [48,64)
        const int j = tid >> 2, g = tid & 3;
        const unsigned int off = (unsigned)(j << 7) +
            (((unsigned)(96 + (g << 3))) ^ ((unsigned)(j & 7) << 4));
        *reinterpret_cast<uint2*>(&efs[off]) = make_uint2(0u, 0u);
    }
    __syncthreads();   // bar1: efs ready

    // ---- folded per-thread LDS bases ----
    const unsigned ge0 = (unsigned)(c << 7) + (((unsigned)(q << 4)) ^ ck);
    const unsigned ge1 = (unsigned)(c << 7) + (((unsigned)(64 | (q << 4))) ^ ck);
    const unsigned we0 = (unsigned)(c << 9) +
        (((unsigned)((w << 6) | (q << 3))) ^ ck);
    const unsigned we1 = (unsigned)(c << 9) +
        (((unsigned)((w << 6) | 32 | (q << 3))) ^ ck);
    const unsigned gr0 = (unsigned)(c << 9) + (((unsigned)(q << 4)) ^ ck);
    const unsigned gr1 = (unsigned)(c << 9) + (((unsigned)(64 | (q << 4))) ^ ck);

    // base rows (thread-constant), pj row base (immediate-indexable)
    f32x4 bb[2];
    #pragma unroll
    for (int mt = 0; mt < 2; ++mt)
        bb[mt] = *reinterpret_cast<const f32x4*>(
            base + ((size_t)bi << 8) + (w << 5) + (mt << 4) + (q << 2));
    const float* pjb = pj + (((size_t)b << 7) + c) * HH + (w << 5) + (q << 2);

    // ------------------ GEMM1: D1[h(32), j(128)] ------------------
    f32x4 acc1[2][8];
    #pragma unroll
    for (int mt = 0; mt < 2; ++mt)
        #pragma unroll
        for (int nt = 0; nt < 8; ++nt) acc1[mt][nt] = f32x4{0.f, 0.f, 0.f, 0.f};

    #pragma unroll
    for (int kk = 0; kk < 2; ++kk) {
        const int koff = (kk << 5) + (q << 3);
        const unsigned geb = kk ? ge1 : ge0;
        f16x8 af[2];
        #pragma unroll
        for (int mt = 0; mt < 2; ++mt) {
            const int row = (w << 5) + (mt << 4) + c;       // h
            af[mt] = *reinterpret_cast<const f16x8*>(WeT + (row << 6) + koff);
        }
        #pragma unroll
        for (int nt = 0; nt < 8; ++nt) {
            const f16x8 bf = *reinterpret_cast<const f16x8*>(
                &efs[geb + (unsigned)(nt << 11)]);
            #pragma unroll
            for (int mt = 0; mt < 2; ++mt)
                acc1[mt][nt] = __builtin_amdgcn_mfma_f32_16x16x32_f16(
                    af[mt], bf, acc1[mt][nt], 0, 0, 0);
        }
    }

    // ---- epi1-A: nt 0..3 (j 0-63) -> h1sA ----
    #pragma unroll
    for (int mt = 0; mt < 2; ++mt) {
        const unsigned web = mt ? we1 : we0;
        #pragma unroll
        for (int nt = 0; nt < 4; ++nt) {
            const f32x4 pjv = *reinterpret_cast<const f32x4*>(
                pjb + (nt << 12) + (mt << 4));
            float s0 = fast_silu(acc1[mt][nt][0] + bb[mt][0] + pjv[0]);
            float s1 = fast_silu(acc1[mt][nt][1] + bb[mt][1] + pjv[1]);
            float s2 = fast_silu(acc1[mt][nt][2] + bb[mt][2] + pjv[2]);
            float s3 = fast_silu(acc1[mt][nt][3] + bb[mt][3] + pjv[3]);
            unsigned int lo = __builtin_bit_cast(unsigned int,
                                __builtin_amdgcn_cvt_pkrtz(s0, s1));
            unsigned int hi = __builtin_bit_cast(unsigned int,
                                __builtin_amdgcn_cvt_pkrtz(s2, s3));
            *reinterpret_cast<uint2*>(&h1sA[web + (unsigned)(nt << 13)]) =
                make_uint2(lo, hi);
        }
    }
    __syncthreads();   // bar2: h1sA ready

    const unsigned short* wp0 = W2T + (((w << 5) + c) << 8) + (q << 3);
    const unsigned short* wp1 = wp0 + (16 << 8);
    float b2v[2];
    #pragma unroll
    for (int nt = 0; nt < 2; ++nt) b2v[nt] = b2[(w << 5) + (nt << 4) + c];

    // ---- phase 3: GEMM2(h1sA) interleaved with epi1-B (nt 4..7 -> h1sB) ----
    f32x4 acc2a[4][2];
    #pragma unroll
    for (int m = 0; m < 4; ++m)
        #pragma unroll
        for (int nt = 0; nt < 2; ++nt) acc2a[m][nt] = f32x4{0.f, 0.f, 0.f, 0.f};

    // prefetch pjv for first B-slice (kk=0 -> nt=4, mt=0)
    f32x4 pjv_n = *reinterpret_cast<const f32x4*>(pjb + (4 << 12));

    #pragma unroll
    for (int kk = 0; kk < 8; ++kk) {
        const f16x8 bw0 = *reinterpret_cast<const f16x8*>(wp0 + (kk << 5));
        const f16x8 bw1 = *reinterpret_cast<const f16x8*>(wp1 + (kk << 5));
        const unsigned grb = ((kk & 1) ? gr1 : gr0) + (unsigned)((kk >> 1) << 7);

        // epi1-B slice for this kk: nt = 4 + kk/2, mt = kk&1
        const int snt = 4 + (kk >> 1);
        const int smt = kk & 1;
        const f32x4 zb = acc1[smt][snt];
        const f32x4 pjv = pjv_n;
        if (kk < 7) {
            const int nnt = 4 + ((kk + 1) >> 1);
            const int nmt = (kk + 1) & 1;
            pjv_n = *reinterpret_cast<const f32x4*>(
                pjb + (nnt << 12) + (nmt << 4));
        }
        float s0 = fast_silu(zb[0] + bb[smt][0] + pjv[0]);
        float s1 = fast_silu(zb[1] + bb[smt][1] + pjv[1]);
        float s2 = fast_silu(zb[2] + bb[smt][2] + pjv[2]);
        float s3 = fast_silu(zb[3] + bb[smt][3] + pjv[3]);
        unsigned int lo = __builtin_bit_cast(unsigned int,
                            __builtin_amdgcn_cvt_pkrtz(s0, s1));
        unsigned int hi = __builtin_bit_cast(unsigned int,
                            __builtin_amdgcn_cvt_pkrtz(s2, s3));
        const unsigned webs = (smt ? we1 : we0) + (unsigned)((snt - 4) << 13);
        *reinterpret_cast<uint2*>(&h1sB[webs]) = make_uint2(lo, hi);

        // GEMM2a kk-step: 2 x (2 a2 reads + 4 MFMA) — bounded frag regs
        #pragma unroll
        for (int g = 0; g < 2; ++g) {
            f16x8 a2[2];
            #pragma unroll
            for (int m = 0; m < 2; ++m) {
                const unsigned M = (unsigned)((g << 1) + m);
                a2[m] = *reinterpret_cast<const f16x8*>(&h1sA[grb + (M << 13)]);
            }
            #pragma unroll
            for (int m = 0; m < 2; ++m) {
                acc2a[(g << 1) + m][0] = __builtin_amdgcn_mfma_f32_16x16x32_f16(
                    a2[m], bw0, acc2a[(g << 1) + m][0], 0, 0, 0);
                acc2a[(g << 1) + m][1] = __builtin_amdgcn_mfma_f32_16x16x32_f16(
                    a2[m], bw1, acc2a[(g << 1) + m][1], 0, 0, 0);
            }
        }
    }
    __syncthreads();   // bar3: h1sB ready

    // ---- phase 4: GEMM2(h1sB) interleaved with epi2 of first half ----
    f32x4 acc2b[4][2];
    #pragma unroll
    for (int m = 0; m < 4; ++m)
        #pragma unroll
        for (int nt = 0; nt < 2; ++nt) acc2b[m][nt] = f32x4{0.f, 0.f, 0.f, 0.f};

    float s[2] = {0.f, 0.f};

    #pragma unroll
    for (int kk = 0; kk < 8; ++kk) {
        const f16x8 bw0 = *reinterpret_cast<const f16x8*>(wp0 + (kk << 5));
        const f16x8 bw1 = *reinterpret_cast<const f16x8*>(wp1 + (kk << 5));
        const unsigned grb = ((kk & 1) ? gr1 : gr0) + (unsigned)((kk >> 1) << 7);

        // epi2-A slice: group (m = kk>>1, n = kk&1): 4 silu-adds
        {
            const int m = kk >> 1, n = kk & 1;
            #pragma unroll
            for (int r = 0; r < 4; ++r)
                s[n] += fast_silu(acc2a[m][n][r] + b2v[n]);
        }

        #pragma unroll
        for (int g = 0; g < 2; ++g) {
            f16x8 a2[2];
            #pragma unroll
            for (int m = 0; m < 2; ++m) {
                const unsigned M = (unsigned)((g << 1) + m);
                a2[m] = *reinterpret_cast<const f16x8*>(&h1sB[grb + (M << 13)]);
            }
            #pragma unroll
            for (int m = 0; m < 2; ++m) {
                acc2b[(g << 1) + m][0] = __builtin_amdgcn_mfma_f32_16x16x32_f16(
                    a2[m], bw0, acc2b[(g << 1) + m][0], 0, 0, 0);
                acc2b[(g << 1) + m][1] = __builtin_amdgcn_mfma_f32_16x16x32_f16(
                    a2[m], bw1, acc2b[(g << 1) + m][1], 0, 0, 0);
            }
        }
    }

    // ---- epi2-B + butterfly + store ----
    #pragma unroll
    for (int nt = 0; nt < 2; ++nt)
        #pragma unroll
        for (int mt = 0; mt < 4; ++mt)
            #pragma unroll
            for (int r = 0; r < 4; ++r)
                s[nt] += fast_silu(acc2b[mt][nt][r] + b2v[nt]);

    #pragma unroll
    for (int nt = 0; nt < 2; ++nt) {
        s[nt] += __shfl_xor(s[nt], 16);
        s[nt] += __shfl_xor(s[nt], 32);
    }
    if (q < 2)
        out[((size_t)bi << 8) + (w << 5) + (q << 4) + c] = s[q] * 0.0078125f;
}

// ---------------------------------------------------------------------------
extern "C" void kernel_launch(void* const* d_in, const int* in_sizes, int n_in,
                              void* d_out, int out_size, void* d_ws, size_t ws_size,
                              hipStream_t stream)
{
    const float* node  = (const float*)d_in[0];
    const float* edge  = (const float*)d_in[1];
    const float* graph = (const float*)d_in[2];
    const float* W1    = (const float*)d_in[3];
    const float* b1    = (const float*)d_in[4];
    const float* W2    = (const float*)d_in[5];
    const float* b2    = (const float*)d_in[6];
    float* out = (float*)d_out;

    char* ws = (char*)d_ws;
    unsigned short* W2T = (unsigned short*)ws;              // 131072 B
    unsigned short* WeT = (unsigned short*)(ws + 131072);   //  32768 B
    float* pj   = (float*)(ws + 163840);                    // 2 MB
    float* base = (float*)(ws + 163840 + 2097152);          // 2 MB

    pre_w     <<<256, 256, 0, stream>>>(W1, W2, W2T, WeT);
    pre_pjbase<<<512, 256, 0, stream>>>(node, graph, W1, b1, pj, base);
    fused_msg <<<BSZ * NN, 512, 0, stream>>>(edge, pj, base, W2T, WeT, b2, out);
}